// Round 8
// baseline (36.409 us; speedup 1.0000x reference)
//
#include <hip/hip_runtime.h>

// GaussianRenderer: N=512 gaussians -> 256x256x3 f32 image. SINGLE KERNEL.
// 512 blocks x 512 thr; block = 64x2 pixel tile. Every block redundantly
// preprocesses all N gaussians into its own LDS (no cross-block comms):
//   phase 1: depth per gaussian -> s_depth
//   phase 2: per-gaussian transform/conic math (1 thr each) + stable rank
//            (128 x wave-uniform ds_read_b128) -> scatter records by rank
//   phase 3: exact ellipse-vs-strip test (rows y0,y0+1) -> ballot -> compact
//   phase 4: broadcast-LDS eval of hits feeding both rows (2 T-chains)
//   phase 5: merge 8 chunk partials (associative over op), coalesced store.
// alpha>=eps  <=>  p00*(dx+c1*dy)^2 + c2*dy^2 <= L2, eps=1e-7 (cull bound
// 512*1e-7=5e-5 abs, threshold 7.6e-4).

constexpr int   WIMG  = 256;
constexpr int   HIMG  = 256;
constexpr int   SPLIT = 8;
constexpr float LOG2E  = 1.4426950408889634f;
constexpr float INV2PI = 0.15915494309189535f;
constexpr float INVEPS = 1.0e7f;                // 1/eps, eps = 1e-7 cull

__global__ __launch_bounds__(512, 4) void gs_fused(
    const float* __restrict__ means3D, const float* __restrict__ covs3d,
    const float* __restrict__ colors,  const float* __restrict__ opac,
    const float* __restrict__ Km,      const float* __restrict__ Rm,
    const float* __restrict__ tvec,    float* __restrict__ out, int N)
{
    __shared__ float  s_depth[512];
    __shared__ float  s_my[512], s_c2[512], s_L2[512], s_c1[512], s_mx[512], s_p0[512];
    __shared__ float  s_ev[512][12];          // 48B rows (16B-aligned)
    __shared__ int    s_hits[SPLIT][64];      // compacted hit indices per wave
    __shared__ float4 s_part[2][SPLIT][64];   // [row][chunk][pixel]
    __shared__ float  s_rgb[2][192];

    const int t = threadIdx.x;

    // ---- Phase 1: depth for gaussian t + defaults for slot t ----
    float d_all = 3.0e38f;
    if (t < N) {
        const float m0 = means3D[t*3+0], m1 = means3D[t*3+1], m2 = means3D[t*3+2];
        d_all = fmaxf(Rm[6]*m0 + Rm[7]*m1 + Rm[8]*m2 + tvec[2], 1.0f);
    }
    s_depth[t] = d_all;
    // slot defaults (only survive where no gaussian scatters, i.e. N<512)
    s_my[t] = 0.0f; s_c2[t] = 0.0f; s_L2[t] = -1e30f;
    s_c1[t] = 0.0f; s_mx[t] = 0.0f; s_p0[t] = 1.0f;
    __syncthreads();

    // ---- Phase 2: heavy math (thread t = gaussian t) + stable rank ----
    float rec[13];
    const bool act = (t < N);
    if (act) {
        float Kl[9], Rl[9], tl[3];
        #pragma unroll
        for (int k = 0; k < 9; ++k) { Kl[k] = Km[k]; Rl[k] = Rm[k]; }
        tl[0] = tvec[0]; tl[1] = tvec[1]; tl[2] = tvec[2];

        const float m0 = means3D[t*3+0], m1 = means3D[t*3+1], m2 = means3D[t*3+2];
        const float cam0 = Rl[0]*m0 + Rl[1]*m1 + Rl[2]*m2 + tl[0];
        const float cam1 = Rl[3]*m0 + Rl[4]*m1 + Rl[5]*m2 + tl[1];
        const float cam2 = Rl[6]*m0 + Rl[7]*m1 + Rl[8]*m2 + tl[2];
        const float Z = cam2;
        const float depth = fmaxf(Z, 1.0f);

        const float s0 = Kl[0]*cam0 + Kl[1]*cam1 + Kl[2]*cam2;
        const float s1 = Kl[3]*cam0 + Kl[4]*cam1 + Kl[5]*cam2;
        const float s2 = Kl[6]*cam0 + Kl[7]*cam1 + Kl[8]*cam2;
        const float mx = s0 / s2, my = s1 / s2;

        const float fx = Kl[0], fy = Kl[4];
        const float iz = 1.0f / Z;
        float J[2][3];
        J[0][0] = fx*iz; J[0][1] = 0.0f;  J[0][2] = -fx*cam0*iz*iz;
        J[1][0] = 0.0f;  J[1][1] = fy*iz; J[1][2] = -fy*cam1*iz*iz;

        float S[9];
        #pragma unroll
        for (int k = 0; k < 9; ++k) S[k] = covs3d[t*9+k];

        float RS[9], Cc[9];
        #pragma unroll
        for (int r = 0; r < 3; ++r)
            #pragma unroll
            for (int c = 0; c < 3; ++c)
                RS[r*3+c] = Rl[r*3+0]*S[0+c] + Rl[r*3+1]*S[3+c] + Rl[r*3+2]*S[6+c];
        #pragma unroll
        for (int r = 0; r < 3; ++r)
            #pragma unroll
            for (int c = 0; c < 3; ++c)
                Cc[r*3+c] = RS[r*3+0]*Rl[c*3+0] + RS[r*3+1]*Rl[c*3+1] + RS[r*3+2]*Rl[c*3+2];

        float JC[2][3];
        #pragma unroll
        for (int r = 0; r < 2; ++r)
            #pragma unroll
            for (int c = 0; c < 3; ++c)
                JC[r][c] = J[r][0]*Cc[0+c] + J[r][1]*Cc[3+c] + J[r][2]*Cc[6+c];

        const float c200 = JC[0][0]*J[0][0] + JC[0][1]*J[0][1] + JC[0][2]*J[0][2] + 1e-4f;
        const float c201 = JC[0][0]*J[1][0] + JC[0][1]*J[1][1] + JC[0][2]*J[1][2];
        const float c210 = JC[1][0]*J[0][0] + JC[1][1]*J[0][1] + JC[1][2]*J[0][2];
        const float c211 = JC[1][0]*J[1][0] + JC[1][1]*J[1][1] + JC[1][2]*J[1][2] + 1e-4f;

        const float det  = c200*c211 - c201*c210;
        const float idet = 1.0f / det;
        const float ia   = c211*idet;                    // P00
        const float i01  = -0.5f*(c201 + c210)*idet;     // P01 (symmetrized)
        const float ic   = c200*idet;                    // P11
        const float ibs  = 2.0f*i01;

        const bool  valid = (depth > 1.0f) && (depth < 50.0f);
        const float nrm   = valid ? (INV2PI / sqrtf(det)) : 0.0f;
        const float opn   = opac[t] * nrm;

        // Exact support test params: Q = ia*(dx+c1*dy)^2 + c2*dy^2 <= L2
        const float c1 = i01 / ia;
        const float c2 = ic - i01*i01/ia;
        const float L2 = 2.0f * logf(opn * INVEPS);      // opn<=0 -> -inf

        rec[0]  = my;  rec[1] = c2;  rec[2] = L2;  rec[3] = c1;
        rec[4]  = mx;  rec[5] = ia;
        rec[6]  = -0.5f*LOG2E*ia;    // A
        rec[7]  = -0.5f*LOG2E*ibs;   // B
        rec[8]  = -0.5f*LOG2E*ic;    // C
        rec[9]  = opn;
        rec[10] = colors[t*3+0];
        rec[11] = colors[t*3+1];
        rec[12] = colors[t*3+2];
    }

    // Stable rank of gaussian t among all depths (wave-uniform b128 reads).
    int rank = 0;
    {
        const float dg = d_all;
        const float4* d4 = (const float4*)s_depth;
        #pragma unroll 4
        for (int j4 = 0; j4 < 128; ++j4) {
            const float4 v = d4[j4];
            const int j = 4*j4;
            rank += (v.x < dg) || (v.x == dg && (j+0) < t);
            rank += (v.y < dg) || (v.y == dg && (j+1) < t);
            rank += (v.z < dg) || (v.z == dg && (j+2) < t);
            rank += (v.w < dg) || (v.w == dg && (j+3) < t);
        }
    }

    if (act) {
        // scatter by rank (stable rank is a bijection -> no write conflicts)
        s_my[rank] = rec[0]; s_c2[rank] = rec[1]; s_L2[rank] = rec[2];
        s_c1[rank] = rec[3]; s_mx[rank] = rec[4]; s_p0[rank] = rec[5];
        float4* ev = (float4*)s_ev[rank];
        ev[0] = make_float4(rec[4], rec[0], rec[6], rec[7]);   // mx,my,A,B
        ev[1] = make_float4(rec[8], rec[9], rec[10], rec[11]); // C,opn,r,g
        s_ev[rank][8] = rec[12];                               // blue
    }
    __syncthreads();

    // ---- Phase 3: exact ellipse test vs rows {y0,y0+1}, ballot, compact ----
    const int w    = t >> 6;
    const int lane = t & 63;
    const int xs   = (int)blockIdx.x & 3;
    const int pr   = (int)blockIdx.x >> 2;             // row pair 0..127
    const float y0f = (float)(2*pr);
    const float sx0 = (float)(xs * 64);
    const float scx = sx0 + 31.5f;                     // strip center x
    const float px  = sx0 + (float)lane;

    const int base = w * 64;
    bool hit;
    {
        const int j = base + lane;
        const float myj = s_my[j], c2 = s_c2[j], L2 = s_L2[j];
        const float c1  = s_c1[j], mxj = s_mx[j], p0 = s_p0[j];
        float dy  = y0f - myj;
        float rem = fmaf(-c2, dy*dy, L2);
        float xc  = fmaf(-c1, dy, mxj);
        float t1  = fmaxf(fabsf(xc - scx) - 31.5f, 0.0f);
        const bool h0 = (p0*t1*t1 <= rem);
        dy  = dy + 1.0f;
        rem = fmaf(-c2, dy*dy, L2);
        xc  = xc - c1;
        t1  = fmaxf(fabsf(xc - scx) - 31.5f, 0.0f);
        const bool h1 = (p0*t1*t1 <= rem);
        hit = h0 | h1;
    }
    const unsigned long long mask = __ballot(hit);
    const int nhit = __popcll(mask);
    if (hit) {
        const int pos = __popcll(mask & ((1ull << lane) - 1ull));
        s_hits[w][pos] = base + lane;     // ascending = sorted depth order
    }
    // s_hits[w] written & read by the same wave only: no barrier needed.

    // ---- Phase 4: eval hits, both rows ----
    float T0 = 1.0f, r0 = 0.0f, g0 = 0.0f, b0 = 0.0f;
    float T1 = 1.0f, r1 = 0.0f, g1 = 0.0f, b1 = 0.0f;

    for (int i = 0; i < nhit; ++i) {
        const int j = s_hits[w][i];                  // broadcast read
        const float* e = s_ev[j];                    // broadcast rows
        const float4 v0 = *(const float4*)(e + 0);   // mx,my,A,B
        const float4 v1 = *(const float4*)(e + 4);   // C,opn,r,g
        const float  bl = e[8];

        const float dx   = px - v0.x;
        const float adx2 = v0.z * dx * dx;           // A*dx^2 (shared)
        const float u    = v0.w * dx;                // B*dx   (shared)
        const float dy0  = y0f - v0.y;
        const float dy1  = dy0 + 1.0f;
        const float e20  = fmaf(dy0, fmaf(v1.x, dy0, u), adx2);
        const float e21  = fmaf(dy1, fmaf(v1.x, dy1, u), adx2);
        const float al0  = v1.y * __builtin_amdgcn_exp2f(e20);
        const float al1  = v1.y * __builtin_amdgcn_exp2f(e21);

        T0 *= (1.0f - al0);                          // cumprod incl. current
        const float w0 = al0 * T0;
        r0 = fmaf(w0, v1.z, r0); g0 = fmaf(w0, v1.w, g0); b0 = fmaf(w0, bl, b0);

        T1 *= (1.0f - al1);
        const float w1 = al1 * T1;
        r1 = fmaf(w1, v1.z, r1); g1 = fmaf(w1, v1.w, g1); b1 = fmaf(w1, bl, b1);
    }

    s_part[0][w][lane] = make_float4(T0, r0, g0, b0);
    s_part[1][w][lane] = make_float4(T1, r1, g1, b1);
    __syncthreads();

    // ---- Phase 5: merge chunk partials + coalesced store ----
    if (t < 128) {
        const int row = t >> 6, p = t & 63;
        float4 f = s_part[row][0][p];
        float Ta = f.x, r_ = f.y, g_ = f.z, b_ = f.w;
        #pragma unroll
        for (int k = 1; k < SPLIT; ++k) {
            const float4 q = s_part[row][k][p];
            r_ = fmaf(Ta, q.y, r_);
            g_ = fmaf(Ta, q.z, g_);
            b_ = fmaf(Ta, q.w, b_);
            Ta *= q.x;
        }
        s_rgb[row][p*3+0] = r_;
        s_rgb[row][p*3+1] = g_;
        s_rgb[row][p*3+2] = b_;
    }
    __syncthreads();

    if (t < 384) {
        const int row = t / 192, i = t - row * 192;
        out[(2*pr + row) * (WIMG*3) + xs*192 + i] = s_rgb[row][i];
    }
}

extern "C" void kernel_launch(void* const* d_in, const int* in_sizes, int n_in,
                              void* d_out, int out_size, void* d_ws, size_t ws_size,
                              hipStream_t stream)
{
    const float* means3D = (const float*)d_in[0];
    const float* covs3d  = (const float*)d_in[1];
    const float* colors  = (const float*)d_in[2];
    const float* opac    = (const float*)d_in[3];
    const float* Km      = (const float*)d_in[4];
    const float* Rm      = (const float*)d_in[5];
    const float* tv      = (const float*)d_in[6];
    const int N = in_sizes[3];               // opacities: (N,)

    float* out = (float*)d_out;

    gs_fused<<<dim3(WIMG * HIMG / 128), dim3(512), 0, stream>>>(
        means3D, covs3d, colors, opac, Km, Rm, tv, out, N);
}

// Round 9
// 16.789 us; speedup vs baseline: 2.1686x; 2.1686x over previous
//
#include <hip/hip_runtime.h>

// GaussianRenderer: N=512 gaussians -> 256x256x3 f32 image.
// K1 (8 blocks x 512 thr): depths (all) + heavy math (wave 0, 1 thr/gaussian)
//   + 8-way-split stable rank; writes sorted 16-float records:
//   [my,c2,L2,c1] [mx,p00,A,B] [C,opn,r,g] [b,-,-,-]
//   where alpha>=eps  <=>  p00*(dx+c1*dy)^2 + c2*dy^2 <= L2  (eps=1e-7).
// K2 (256 blocks x 512 thr): 64x4 quad-row tile per block (1 block/CU).
//   Stage records to LDS once; wave w owns chunk w: exact ellipse test vs
//   rows {y0..y0+3} -> ballot -> compacted hit list -> broadcast-LDS eval
//   feeding ALL 4 rows (shared dx terms, 4 independent T-chains).
//   8 chunk partials per row merged with the associative over op; coalesced
//   store. (R8 lesson: do NOT fuse — per-block redundant rank is LDS-bound.)

constexpr int   REC   = 16;     // floats per sorted record (64B)
constexpr int   WIMG  = 256;
constexpr int   HIMG  = 256;
constexpr int   SPLIT = 8;
constexpr float LOG2E  = 1.4426950408889634f;
constexpr float INV2PI = 0.15915494309189535f;
constexpr float INVEPS = 1.0e7f;                // 1/eps, eps = 1e-7 cull

__global__ __launch_bounds__(512) void gs_preprocess(
    const float* __restrict__ means3D, const float* __restrict__ covs3d,
    const float* __restrict__ colors,  const float* __restrict__ opac,
    const float* __restrict__ Km,      const float* __restrict__ Rm,
    const float* __restrict__ tvec,    float* __restrict__ recs, int N)
{
    __shared__ float s_depth[512];
    __shared__ int   s_cnt[64][9];          // [gaussian][partial], padded
    const int t  = threadIdx.x;
    const int l  = t & 63, p = t >> 6;
    const int gi = (int)blockIdx.x * 64 + l;

    // Phase A: all threads -> depth of slot t (pad +inf)
    float d_all = 3.0e38f;
    if (t < N) {
        const float m0 = means3D[t*3+0], m1 = means3D[t*3+1], m2 = means3D[t*3+2];
        d_all = fmaxf(Rm[6]*m0 + Rm[7]*m1 + Rm[8]*m2 + tvec[2], 1.0f);
    }
    s_depth[t] = d_all;
    __syncthreads();

    // Phase B: 8-way split stable rank partial for gaussian gi
    const float dg = s_depth[gi & 511];
    int cnt = 0;
    #pragma unroll 16
    for (int j = p*64; j < p*64 + 64; ++j) {
        const float dj = s_depth[j];
        cnt += (dj < dg) || (dj == dg && j < gi);
    }
    s_cnt[l][p] = cnt;

    // Phase C: heavy per-gaussian math on p==0 threads
    float rec[13];
    const bool act = (p == 0) && (gi < N);
    if (act) {
        float Kl[9], Rl[9], tl[3];
        #pragma unroll
        for (int k = 0; k < 9; ++k) { Kl[k] = Km[k]; Rl[k] = Rm[k]; }
        tl[0] = tvec[0]; tl[1] = tvec[1]; tl[2] = tvec[2];

        const float m0 = means3D[gi*3+0], m1 = means3D[gi*3+1], m2 = means3D[gi*3+2];
        const float cam0 = Rl[0]*m0 + Rl[1]*m1 + Rl[2]*m2 + tl[0];
        const float cam1 = Rl[3]*m0 + Rl[4]*m1 + Rl[5]*m2 + tl[1];
        const float cam2 = Rl[6]*m0 + Rl[7]*m1 + Rl[8]*m2 + tl[2];
        const float Z = cam2;
        const float depth = fmaxf(Z, 1.0f);

        const float s0 = Kl[0]*cam0 + Kl[1]*cam1 + Kl[2]*cam2;
        const float s1 = Kl[3]*cam0 + Kl[4]*cam1 + Kl[5]*cam2;
        const float s2 = Kl[6]*cam0 + Kl[7]*cam1 + Kl[8]*cam2;
        const float mx = s0 / s2, my = s1 / s2;

        const float fx = Kl[0], fy = Kl[4];
        const float iz = 1.0f / Z;
        float J[2][3];
        J[0][0] = fx*iz; J[0][1] = 0.0f;  J[0][2] = -fx*cam0*iz*iz;
        J[1][0] = 0.0f;  J[1][1] = fy*iz; J[1][2] = -fy*cam1*iz*iz;

        float S[9];
        #pragma unroll
        for (int k = 0; k < 9; ++k) S[k] = covs3d[gi*9+k];

        float RS[9], Cc[9];
        #pragma unroll
        for (int r = 0; r < 3; ++r)
            #pragma unroll
            for (int c = 0; c < 3; ++c)
                RS[r*3+c] = Rl[r*3+0]*S[0+c] + Rl[r*3+1]*S[3+c] + Rl[r*3+2]*S[6+c];
        #pragma unroll
        for (int r = 0; r < 3; ++r)
            #pragma unroll
            for (int c = 0; c < 3; ++c)
                Cc[r*3+c] = RS[r*3+0]*Rl[c*3+0] + RS[r*3+1]*Rl[c*3+1] + RS[r*3+2]*Rl[c*3+2];

        float JC[2][3];
        #pragma unroll
        for (int r = 0; r < 2; ++r)
            #pragma unroll
            for (int c = 0; c < 3; ++c)
                JC[r][c] = J[r][0]*Cc[0+c] + J[r][1]*Cc[3+c] + J[r][2]*Cc[6+c];

        const float c200 = JC[0][0]*J[0][0] + JC[0][1]*J[0][1] + JC[0][2]*J[0][2] + 1e-4f;
        const float c201 = JC[0][0]*J[1][0] + JC[0][1]*J[1][1] + JC[0][2]*J[1][2];
        const float c210 = JC[1][0]*J[0][0] + JC[1][1]*J[0][1] + JC[1][2]*J[0][2];
        const float c211 = JC[1][0]*J[1][0] + JC[1][1]*J[1][1] + JC[1][2]*J[1][2] + 1e-4f;

        const float det  = c200*c211 - c201*c210;
        const float idet = 1.0f / det;
        const float ia   = c211*idet;                    // P00
        const float i01  = -0.5f*(c201 + c210)*idet;     // P01 (symmetrized)
        const float ic   = c200*idet;                    // P11
        const float ibs  = 2.0f*i01;

        const bool  valid = (depth > 1.0f) && (depth < 50.0f);
        const float nrm   = valid ? (INV2PI / sqrtf(det)) : 0.0f;
        const float opn   = opac[gi] * nrm;

        // Exact support test params: Q = ia*(dx+c1*dy)^2 + c2*dy^2 <= L2
        const float c1 = i01 / ia;
        const float c2 = ic - i01*i01/ia;
        const float L2 = 2.0f * logf(opn * INVEPS);      // opn<=0 -> -inf

        rec[0]  = my;  rec[1] = c2;  rec[2] = L2;  rec[3] = c1;
        rec[4]  = mx;  rec[5] = ia;
        rec[6]  = -0.5f*LOG2E*ia;    // A
        rec[7]  = -0.5f*LOG2E*ibs;   // B
        rec[8]  = -0.5f*LOG2E*ic;    // C
        rec[9]  = opn;
        rec[10] = colors[gi*3+0];
        rec[11] = colors[gi*3+1];
        rec[12] = colors[gi*3+2];
    }
    __syncthreads();

    if (act) {
        int rank = 0;
        #pragma unroll
        for (int q = 0; q < 8; ++q) rank += s_cnt[l][q];
        float4* dst = (float4*)(recs + rank*REC);
        dst[0] = make_float4(rec[0],  rec[1],  rec[2],  rec[3]);
        dst[1] = make_float4(rec[4],  rec[5],  rec[6],  rec[7]);
        dst[2] = make_float4(rec[8],  rec[9],  rec[10], rec[11]);
        dst[3] = make_float4(rec[12], 0.0f,    0.0f,    0.0f);
    }
}

// Block: 512 thr = 8 waves; 64x4 quad-row tile. Records LDS-staged once.
__global__ __launch_bounds__(512, 2) void gs_render(
    const float* __restrict__ recs, float* __restrict__ out, int N)
{
    __shared__ float  s_my[512], s_c2[512], s_L2[512], s_c1[512], s_mx[512], s_p0[512];
    __shared__ float  s_ev[512][12];          // 48B rows (16B-aligned)
    __shared__ int    s_hits[SPLIT][64];      // compacted hit indices per wave
    __shared__ float4 s_part[4][SPLIT][64];   // [row][chunk][pixel]
    __shared__ float  s_rgb[4][192];

    const int t = threadIdx.x;

    // Stage: thread t handles record t.
    if (t < N) {
        const float4 a = *(const float4*)(recs + t*REC + 0);   // my,c2,L2,c1
        const float4 b = *(const float4*)(recs + t*REC + 4);   // mx,p00,A,B
        const float4 c = *(const float4*)(recs + t*REC + 8);   // C,opn,r,g
        const float4 d = *(const float4*)(recs + t*REC + 12);  // b,-,-,-
        s_my[t] = a.x; s_c2[t] = a.y; s_L2[t] = a.z; s_c1[t] = a.w;
        s_mx[t] = b.x; s_p0[t] = b.y;
        float4* ev = (float4*)s_ev[t];
        ev[0] = make_float4(b.x, a.x, b.z, b.w);   // mx, my, A, B
        ev[1] = make_float4(c.x, c.y, c.z, c.w);   // C, opn, r, g
        s_ev[t][8] = d.x;                          // blue
    } else {
        s_my[t] = 0.0f; s_c2[t] = 0.0f; s_L2[t] = -1e30f;
        s_c1[t] = 0.0f; s_mx[t] = 0.0f; s_p0[t] = 1.0f;
    }
    __syncthreads();

    const int w    = t >> 6;
    const int lane = t & 63;
    const int xs   = (int)blockIdx.x & 3;
    const int qr   = (int)blockIdx.x >> 2;             // quad-row 0..63
    const float y0f = (float)(4*qr);
    const float sx0 = (float)(xs * 64);
    const float scx = sx0 + 31.5f;                     // strip center x
    const float px  = sx0 + (float)lane;

    // Lane-parallel EXACT ellipse test vs rows {y0..y0+3} for chunk w.
    const int base = w * 64;
    bool hit = false;
    {
        const int j = base + lane;
        const float myj = s_my[j], c2 = s_c2[j], L2 = s_L2[j];
        const float c1  = s_c1[j], mxj = s_mx[j], p0 = s_p0[j];
        float dy = y0f - myj;
        float xc = fmaf(-c1, dy, mxj);
        #pragma unroll
        for (int r = 0; r < 4; ++r) {
            const float rem = fmaf(-c2, dy*dy, L2);
            const float t1  = fmaxf(fabsf(xc - scx) - 31.5f, 0.0f);
            hit = hit || (p0*t1*t1 <= rem);
            dy += 1.0f;
            xc -= c1;
        }
    }
    const unsigned long long mask = __ballot(hit);
    const int nhit = __popcll(mask);
    if (hit) {
        const int pos = __popcll(mask & ((1ull << lane) - 1ull));
        s_hits[w][pos] = base + lane;     // ascending = sorted depth order
    }
    // s_hits[w] written & read by the same wave only: no barrier needed.

    // Eval hits, 4 rows per iteration (shared dx terms, 4 T-chains).
    float T0 = 1.0f, r0 = 0.0f, g0 = 0.0f, b0 = 0.0f;
    float T1 = 1.0f, r1 = 0.0f, g1 = 0.0f, b1 = 0.0f;
    float T2 = 1.0f, r2 = 0.0f, g2 = 0.0f, b2 = 0.0f;
    float T3 = 1.0f, r3 = 0.0f, g3 = 0.0f, b3 = 0.0f;

    for (int i = 0; i < nhit; ++i) {
        const int j = s_hits[w][i];                  // broadcast read
        const float* e = s_ev[j];                    // broadcast rows
        const float4 v0 = *(const float4*)(e + 0);   // mx,my,A,B
        const float4 v1 = *(const float4*)(e + 4);   // C,opn,r,g
        const float  bl = e[8];

        const float dx   = px - v0.x;
        const float adx2 = v0.z * dx * dx;           // A*dx^2 (shared)
        const float u    = v0.w * dx;                // B*dx   (shared)
        const float dy0  = y0f - v0.y;
        const float dy1  = dy0 + 1.0f;
        const float dy2  = dy0 + 2.0f;
        const float dy3  = dy0 + 3.0f;
        const float e20  = fmaf(dy0, fmaf(v1.x, dy0, u), adx2);
        const float e21  = fmaf(dy1, fmaf(v1.x, dy1, u), adx2);
        const float e22  = fmaf(dy2, fmaf(v1.x, dy2, u), adx2);
        const float e23  = fmaf(dy3, fmaf(v1.x, dy3, u), adx2);
        const float al0  = v1.y * __builtin_amdgcn_exp2f(e20);
        const float al1  = v1.y * __builtin_amdgcn_exp2f(e21);
        const float al2  = v1.y * __builtin_amdgcn_exp2f(e22);
        const float al3  = v1.y * __builtin_amdgcn_exp2f(e23);

        T0 *= (1.0f - al0);                          // cumprod incl. current
        const float w0 = al0 * T0;
        r0 = fmaf(w0, v1.z, r0); g0 = fmaf(w0, v1.w, g0); b0 = fmaf(w0, bl, b0);

        T1 *= (1.0f - al1);
        const float w1 = al1 * T1;
        r1 = fmaf(w1, v1.z, r1); g1 = fmaf(w1, v1.w, g1); b1 = fmaf(w1, bl, b1);

        T2 *= (1.0f - al2);
        const float w2 = al2 * T2;
        r2 = fmaf(w2, v1.z, r2); g2 = fmaf(w2, v1.w, g2); b2 = fmaf(w2, bl, b2);

        T3 *= (1.0f - al3);
        const float w3 = al3 * T3;
        r3 = fmaf(w3, v1.z, r3); g3 = fmaf(w3, v1.w, g3); b3 = fmaf(w3, bl, b3);
    }

    s_part[0][w][lane] = make_float4(T0, r0, g0, b0);
    s_part[1][w][lane] = make_float4(T1, r1, g1, b1);
    s_part[2][w][lane] = make_float4(T2, r2, g2, b2);
    s_part[3][w][lane] = make_float4(T3, r3, g3, b3);
    __syncthreads();

    // Merge chunk partials (4 rows x 64 px = 256 threads) + coalesced store.
    if (t < 256) {
        const int row = t >> 6, p = t & 63;
        float4 f = s_part[row][0][p];
        float Ta = f.x, r_ = f.y, g_ = f.z, b_ = f.w;
        #pragma unroll
        for (int k = 1; k < SPLIT; ++k) {
            const float4 q = s_part[row][k][p];
            r_ = fmaf(Ta, q.y, r_);
            g_ = fmaf(Ta, q.z, g_);
            b_ = fmaf(Ta, q.w, b_);
            Ta *= q.x;
        }
        s_rgb[row][p*3+0] = r_;
        s_rgb[row][p*3+1] = g_;
        s_rgb[row][p*3+2] = b_;
    }
    __syncthreads();

    #pragma unroll
    for (int k = t; k < 768; k += 512) {
        const int row = k / 192;
        const int i   = k - row * 192;
        out[(4*qr + row) * (WIMG*3) + xs*192 + i] = s_rgb[row][i];
    }
}

extern "C" void kernel_launch(void* const* d_in, const int* in_sizes, int n_in,
                              void* d_out, int out_size, void* d_ws, size_t ws_size,
                              hipStream_t stream)
{
    const float* means3D = (const float*)d_in[0];
    const float* covs3d  = (const float*)d_in[1];
    const float* colors  = (const float*)d_in[2];
    const float* opac    = (const float*)d_in[3];
    const float* Km      = (const float*)d_in[4];
    const float* Rm      = (const float*)d_in[5];
    const float* tv      = (const float*)d_in[6];
    const int N = in_sizes[3];               // opacities: (N,)

    float* recs = (float*)d_ws;              // N*REC floats = 32 KB
    float* out  = (float*)d_out;

    gs_preprocess<<<dim3((N + 63) / 64), dim3(512), 0, stream>>>(
        means3D, covs3d, colors, opac, Km, Rm, tv, recs, N);

    gs_render<<<dim3(WIMG * HIMG / 256), dim3(512), 0, stream>>>(recs, out, N);
}